// Round 23
// baseline (153.752 us; speedup 1.0000x reference)
//
#include <hip/hip_runtime.h>
#include <math.h>

#define BATCH 4
#define SEQ   2048
#define DM    1024
#define NTOK  (BATCH * SEQ)   // 8192

typedef __attribute__((ext_vector_type(8))) short bf16x8;
typedef __attribute__((ext_vector_type(4))) float f32x4;
typedef unsigned short u16;
struct alignas(8) us4 { u16 x, y, z, w; };

__device__ __forceinline__ u16 f2bf(float f) {
    union { float f; unsigned u; } v; v.f = f;
    unsigned r = v.u + 0x7fffu + ((v.u >> 16) & 1u);   // round-to-nearest-even
    return (u16)(r >> 16);
}

__device__ __forceinline__ void gload_lds16(const void* g, void* l) {
    __builtin_amdgcn_global_load_lds(
        (const __attribute__((address_space(1))) unsigned int*)g,
        (__attribute__((address_space(3))) unsigned int*)l, 16, 0, 0);
}

#define VM0 asm volatile("s_waitcnt vmcnt(0)" ::: "memory")
#define BAR __builtin_amdgcn_s_barrier()

// read one 16x16x32 fragment from a swizzled [128/256][64] tile
// (rows of 128 B, byte ^= (row&7)<<4 — conflict-free, verified R11/R13)
__device__ __forceinline__ bf16x8 ldsF(const u16* T, int fr, int kk, int lane)
{
    const int row  = fr * 16 + (lane & 15);
    const int colb = (kk * 64 + ((lane >> 4) << 4)) ^ ((row & 7) << 4);
    return *(const bf16x8*)(T + row * 64 + (colb >> 1));
}

// ===========================================================================
// qkv: 256x256 8-wave GEMM, one barrier per K-tile, R19 stage placement,
// R21 LDS-transpose vT epilogue; R22b adds the same coalescing trick for
// q/k rows (LDS [mloc][nloc], swz byte^=(mloc&7)<<4, 512B row stores).
// ===========================================================================

// stage one 128-row x 64-k half (16 KB): 512 thr x 2 x 16 B
__device__ __forceinline__ void stageH(const u16* __restrict__ G, int ld,
    int row0, int kt, u16* half_lds, int wid, int lane)
{
    #pragma unroll
    for (int j = 0; j < 2; ++j) {
        const int base = j * 8192 + wid * 1024;           // dest byte
        const int off  = base + lane * 16;
        const int row  = off >> 7;                        // 0..127
        const int colb = (off & 127) ^ ((row & 7) << 4);  // inv-swz source col
        gload_lds16(G + (size_t)(row0 + row) * ld + kt + (colb >> 1),
                    (char*)half_lds + base);
    }
}

template<int MB, int NB>
__device__ __forceinline__ void mma16(const bf16x8 A[4][2], const bf16x8 B[2][2],
                                      f32x4 acc[8][4])
{
    __builtin_amdgcn_s_setprio(1);
    #pragma unroll
    for (int i = 0; i < 4; ++i)
        #pragma unroll
        for (int j = 0; j < 2; ++j)
            #pragma unroll
            for (int kk = 0; kk < 2; ++kk)
                acc[MB + i][NB + j] = __builtin_amdgcn_mfma_f32_16x16x32_bf16(
                    A[i][kk], B[j][kk], acc[MB + i][NB + j], 0, 0, 0);
    __builtin_amdgcn_s_setprio(0);
}

__global__ __launch_bounds__(512, 2) void qkv_mfma8(
    const u16* __restrict__ xb,
    const u16* __restrict__ wqb, const float* __restrict__ bq,
    const u16* __restrict__ wkb, const float* __restrict__ bk,
    const u16* __restrict__ wvb, const float* __restrict__ bv,
    u16* __restrict__ qb, u16* __restrict__ kb, u16* __restrict__ vT)
{
    __shared__ alignas(16) u16 LDS[65536];   // 128 KB
    const int z = blockIdx.z;
    const u16* W = (z == 0) ? wqb : (z == 1) ? wkb : wvb;
    const float* bias = (z == 0) ? bq : (z == 1) ? bk : bv;
    const int m0 = blockIdx.x * 256, n0 = blockIdx.y * 256;
    const int t = threadIdx.x, wid = t >> 6, lane = t & 63;
    const int wm = wid >> 2, wn = wid & 3;

    f32x4 acc[8][4] = {};

    // prologue: stage ALL 4 halves of tile 0 into parity-0 buffers
    stageH(xb, DM, m0,       0, LDS + 0,            wid, lane);  // A0 t0
    stageH(xb, DM, m0 + 128, 0, LDS + 8192,         wid, lane);  // A1 t0
    stageH(W,  DM, n0,       0, LDS + 32768,        wid, lane);  // B0 t0
    stageH(W,  DM, n0 + 128, 0, LDS + 32768 + 8192, wid, lane);  // B1 t0
    VM0;
    BAR;

    bf16x8 rA0[4][2], rA1[4][2], rB[2][2];

    #pragma unroll 1
    for (int ti = 0; ti < 16; ++ti) {
        const int cur = ti & 1, nxt = cur ^ 1;
        u16* Ac0 = LDS + cur * 16384;
        u16* Ac1 = Ac0 + 8192;
        u16* Bc0 = LDS + 32768 + cur * 16384;
        u16* Bc1 = Bc0 + 8192;
        u16* An0 = LDS + nxt * 16384;
        u16* An1 = An0 + 8192;
        u16* Bn0 = LDS + 32768 + nxt * 16384;
        u16* Bn1 = Bn0 + 8192;
        const int kt1 = (ti + 1) * 64;
        const bool st = ti < 15;

        // ---- straight-line region (R19 placement: stages interleaved) ----
        #pragma unroll
        for (int i = 0; i < 4; ++i) {
            rA0[i][0] = ldsF(Ac0, 2 * i + wm, 0, lane);
            rA0[i][1] = ldsF(Ac0, 2 * i + wm, 1, lane);
        }
        #pragma unroll
        for (int j = 0; j < 2; ++j) {
            rB[j][0] = ldsF(Bc0, 4 * j + wn, 0, lane);
            rB[j][1] = ldsF(Bc0, 4 * j + wn, 1, lane);
        }
        if (st) {
            stageH(xb, DM, m0,       kt1, An0, wid, lane);
            stageH(W,  DM, n0,       kt1, Bn0, wid, lane);
        }
        mma16<0, 0>(rA0, rB, acc);

        #pragma unroll
        for (int i = 0; i < 4; ++i) {
            rA1[i][0] = ldsF(Ac1, 2 * i + wm, 0, lane);
            rA1[i][1] = ldsF(Ac1, 2 * i + wm, 1, lane);
        }
        if (st) stageH(xb, DM, m0 + 128, kt1, An1, wid, lane);
        mma16<4, 0>(rA1, rB, acc);

        #pragma unroll
        for (int j = 0; j < 2; ++j) {
            rB[j][0] = ldsF(Bc1, 4 * j + wn, 0, lane);
            rB[j][1] = ldsF(Bc1, 4 * j + wn, 1, lane);
        }
        if (st) stageH(W, DM, n0 + 128, kt1, Bn1, wid, lane);
        mma16<4, 2>(rA1, rB, acc);

        mma16<0, 2>(rA0, rB, acc);

        // ---- single sync point per K-tile ----
        VM0;
        BAR;
    }

    const int lrow = lane & 15, lhi = lane >> 4;
    if (z < 2) {
        // ---- q/k rows via LDS: [mloc][nloc] swz, 512B coalesced stores ----
        u16* outp = (z == 0) ? qb : kb;
        #pragma unroll
        for (int nf = 0; nf < 4; ++nf) {
            const int nloc = (4 * nf + wn) * 16 + lrow;
            const float bn = bias[n0 + nloc];
            #pragma unroll
            for (int mf = 0; mf < 8; ++mf) {
                const int mloc0 = (2 * mf + wm) * 16 + lhi * 4;
                #pragma unroll
                for (int r = 0; r < 4; ++r) {
                    const int mloc = mloc0 + r;
                    const int bidx = (mloc * 512 + nloc * 2)
                                     ^ ((mloc & 7) << 4);
                    *(u16*)((char*)LDS + bidx) = f2bf(acc[mf][nf][r] + bn);
                }
            }
        }
        BAR;
        const int c = t & 31;            // 16B chunk within the 512B row
        #pragma unroll 1
        for (int rr = t >> 5; rr < 256; rr += 16) {
            const int bidx = rr * 512 + ((c * 16) ^ ((rr & 7) << 4));
            bf16x8 v = *(const bf16x8*)((char*)LDS + bidx);
            *(bf16x8*)(outp + (size_t)(m0 + rr) * DM + n0 + c * 8) = v;
        }
    } else {
        // ---- vT via LDS transpose (R21, measured win) ----
        #pragma unroll
        for (int nf = 0; nf < 4; ++nf) {
            const int nloc = nf * 16 + lrow;
            const int n = n0 + (4 * nf + wn) * 16 + lrow;
            const float bn = bias[n];
            #pragma unroll
            for (int mf = 0; mf < 8; ++mf) {
                const int mloc0 = (2 * mf + wm) * 16 + lhi * 4;
                const int idx = (wn * 16384 + nloc * 256 + mloc0)
                                ^ ((nloc & 7) << 3);
                us4 p{f2bf(acc[mf][nf][0] + bn), f2bf(acc[mf][nf][1] + bn),
                      f2bf(acc[mf][nf][2] + bn), f2bf(acc[mf][nf][3] + bn)};
                *(us4*)(LDS + idx) = p;
            }
        }
        BAR;
        const int c = t & 31;            // 16B chunk within the 512B row
        #pragma unroll 1
        for (int rr = t >> 5; rr < 256; rr += 16) {
            const int lr2 = rr & 15, wn2 = (rr >> 4) & 3, nf2 = rr >> 6;
            const int nloc = nf2 * 16 + lr2;
            const int idx = (wn2 * 16384 + nloc * 256 + c * 8)
                            ^ ((nloc & 7) << 3);
            bf16x8 v = *(const bf16x8*)(LDS + idx);
            *(bf16x8*)(vT + (size_t)(n0 + rr) * NTOK + m0 + c * 8) = v;
        }
    }
}

// ===========================================================================
// qk / pv: BK=64 + swizzle, 2-barrier 128x128 structure.
// ===========================================================================

// Stage a 128-row x 64-k bf16 tile (16 KB) into swizzled LDS, 256 thr.
__device__ __forceinline__ void stage64(const u16* __restrict__ G, int ld,
    int row0, int kt, u16* lds, int wid, int lane)
{
    #pragma unroll
    for (int j = 0; j < 4; ++j) {
        const int base = j * 4096 + wid * 1024;
        const int off  = base + lane * 16;
        const int row  = off >> 7;
        const int colb = (off & 127) ^ ((row & 7) << 4);
        gload_lds16(G + (size_t)(row0 + row) * ld + kt + (colb >> 1),
                    (char*)lds + base);
    }
}

// 16 ds_reads -> 32 MFMAs per K=64 tile (4 waves, 64x64 each)
__device__ __forceinline__ void frag_mma64(
    const u16* As, const u16* Bs, int wr, int wc, int lane, f32x4 acc[4][4])
{
    #pragma unroll
    for (int kk = 0; kk < 2; ++kk) {
        bf16x8 a[4], b[4];
        #pragma unroll
        for (int i = 0; i < 4; ++i) a[i] = ldsF(As, wr * 4 + i, kk, lane);
        #pragma unroll
        for (int j = 0; j < 4; ++j) b[j] = ldsF(Bs, wc * 4 + j, kk, lane);
        #pragma unroll
        for (int i = 0; i < 4; ++i)
            #pragma unroll
            for (int j = 0; j < 4; ++j)
                acc[i][j] = __builtin_amdgcn_mfma_f32_16x16x32_bf16(
                    a[i], b[j], acc[i][j], 0, 0, 0);
    }
}

// ---------------------------------------------------------------------------
// f32 -> bf16 convert: flat balanced grid over all four arrays (66 MB total).
// ---------------------------------------------------------------------------
__global__ __launch_bounds__(256) void conv_flat(
    const float* __restrict__ x,
    const float* __restrict__ w0, const float* __restrict__ w1,
    const float* __restrict__ w2,
    u16* __restrict__ xo,
    u16* __restrict__ o0, u16* __restrict__ o1, u16* __restrict__ o2)
{
    const int X4  = NTOK * DM / 4;     // 2,097,152 float4s
    const int W4  = DM * DM / 4;       //   262,144 float4s
    const int TOT = X4 + 3 * W4;
    for (int i = blockIdx.x * 256 + threadIdx.x; i < TOT; i += gridDim.x * 256) {
        const float* in; u16* out; int idx;
        if (i < X4) { in = x; out = xo; idx = i; }
        else {
            const int j = i - X4, s = j >> 18;       // /W4 (2^18)
            idx = j & (W4 - 1);
            in  = (s == 0) ? w0 : (s == 1) ? w1 : w2;
            out = (s == 0) ? o0 : (s == 1) ? o1 : o2;
        }
        float4 f = ((const float4*)in)[idx];
        us4 p{f2bf(f.x), f2bf(f.y), f2bf(f.z), f2bf(f.w)};
        ((us4*)out)[idx] = p;
    }
}

// qk: triangular grid — only the 136 lower-triangle (m,n) pairs per batch.
__global__ __launch_bounds__(256, 3) void qk_exp(
    const u16* __restrict__ qb, const u16* __restrict__ kb,
    u16* __restrict__ attn, float* __restrict__ psum)
{
    // decode triangular index: blockIdx.x in [0,136)
    int ti = blockIdx.x, mi = 0;
    while (ti >= mi + 1) { ti -= mi + 1; ++mi; }     // mi 0..15, ti = ni
    const int m0 = mi * 128, n0 = ti * 128;
    __shared__ u16 As[128 * 64], Bs[128 * 64];   // 32 KB
    const int b = blockIdx.z;
    const u16* A = qb + (size_t)b * SEQ * DM;
    const u16* B = kb + (size_t)b * SEQ * DM;
    u16* P = attn + (size_t)b * SEQ * SEQ;
    const int t = threadIdx.x, wid = t >> 6, lane = t & 63;
    const int wr = wid >> 1, wc = wid & 1;

    f32x4 acc[4][4] = {};
    for (int kt = 0; kt < DM; kt += 64) {
        __syncthreads();
        stage64(A, DM, m0, kt, As, wid, lane);
        stage64(B, DM, n0, kt, Bs, wid, lane);
        __syncthreads();
        frag_mma64(As, Bs, wr, wc, lane, acc);
    }
    const int lrow = lane & 15, lg = lane >> 4;
    const float scale = 0.03125f;
    const int nb = (n0 >> 6) | wc;
    #pragma unroll
    for (int mi2 = 0; mi2 < 4; ++mi2) {
        #pragma unroll
        for (int r = 0; r < 4; ++r) {
            const int row = m0 + wr * 64 + mi2 * 16 + lg * 4 + r;
            float ps = 0.f;
            #pragma unroll
            for (int ni = 0; ni < 4; ++ni) {
                const int n = n0 + wc * 64 + ni * 16 + lrow;
                const float p = (n <= row) ? __expf(acc[mi2][ni][r] * scale) : 0.f;
                P[(size_t)row * SEQ + n] = f2bf(p);
                ps += p;
            }
            #pragma unroll
            for (int mk = 1; mk < 16; mk <<= 1) ps += __shfl_xor(ps, mk);
            if (lrow == 0)
                psum[((size_t)b * SEQ + row) * 32 + nb] = ps;
        }
    }
}

// pv: 1-D grid (512) with XCD-clustering swizzle (bijective, perf-only).
__global__ __launch_bounds__(256, 3) void pv_mfma(
    const u16* __restrict__ attn, const u16* __restrict__ vT,
    const float* __restrict__ psum, float* __restrict__ out)
{
    __shared__ u16 As[128 * 64], Bs[128 * 64];   // 32 KB
    __shared__ float invs[128];
    const int bid = blockIdx.x;
    const int xcd = bid & 7, rdec = bid >> 3;
    const int n0i = rdec & 7, ghi = rdec >> 3;
    const int g = ghi * 8 + xcd;          // g = m0i + 16*b
    const int m0 = (g & 15) * 128, n0 = n0i * 128;
    const int b = g >> 4;
    const u16* A = attn + (size_t)b * SEQ * SEQ;
    const u16* B = vT + (size_t)b * SEQ;
    float* C = out + (size_t)b * SEQ * DM;
    const int t = threadIdx.x, wid = t >> 6, lane = t & 63;
    const int wr = wid >> 1, wc = wid & 1;

    if (t < 128) {
        const int row = m0 + t;
        const float* pr = psum + ((size_t)b * SEQ + row) * 32;
        const int nbmax = (row >> 6) | 1;
        float s = 0.f;
        for (int nbi = 0; nbi <= nbmax; ++nbi) s += pr[nbi];
        invs[t] = 1.f / s;
    }

    f32x4 acc[4][4] = {};
    const int kmax = m0 + 128;
    for (int kt = 0; kt < kmax; kt += 64) {
        __syncthreads();
        stage64(A, SEQ,  m0, kt, As, wid, lane);
        stage64(B, NTOK, n0, kt, Bs, wid, lane);
        __syncthreads();
        frag_mma64(As, Bs, wr, wc, lane, acc);
    }
    const int lrow = lane & 15, lg = lane >> 4;
    #pragma unroll
    for (int mi = 0; mi < 4; ++mi) {
        const int ml = wr * 64 + mi * 16 + lg * 4;
        #pragma unroll
        for (int ni = 0; ni < 4; ++ni) {
            const int n = n0 + wc * 64 + ni * 16 + lrow;
            #pragma unroll
            for (int r = 0; r < 4; ++r)
                C[(size_t)(m0 + ml + r) * DM + n] = acc[mi][ni][r] * invs[ml + r];
        }
    }
}

// ---------------------------------------------------------------------------
extern "C" void kernel_launch(void* const* d_in, const int* in_sizes, int n_in,
                              void* d_out, int out_size, void* d_ws, size_t ws_size,
                              hipStream_t stream)
{
    const float* x  = (const float*)d_in[0];
    const float* wq = (const float*)d_in[1];
    const float* bq = (const float*)d_in[2];
    const float* wk = (const float*)d_in[3];
    const float* bk = (const float*)d_in[4];
    const float* wv = (const float*)d_in[5];
    const float* bv = (const float*)d_in[6];
    float* out = (float*)d_out;

    u16* ws  = (u16*)d_ws;
    u16* xb  = ws;
    u16* wqb = xb  + (size_t)NTOK * DM;
    u16* wkb = wqb + (size_t)DM * DM;
    u16* wvb = wkb + (size_t)DM * DM;
    u16* qb  = wvb + (size_t)DM * DM;
    u16* kb  = qb  + (size_t)NTOK * DM;
    u16* vT  = kb  + (size_t)NTOK * DM;        // [DM][NTOK]
    u16* attn = vT + (size_t)NTOK * DM;        // bf16 [B][SEQ][SEQ]
    float* psum = (float*)(attn + (size_t)BATCH * SEQ * SEQ);  // [B][SEQ][32]

    conv_flat<<<2048, 256, 0, stream>>>(
        x, wq, wk, wv, xb, wqb, wkb, wvb);

    qkv_mfma8<<<dim3(NTOK / 256, DM / 256, 3), 512, 0, stream>>>(
        xb, wqb, bq, wkb, bk, wvb, bv, qb, kb, vT);

    qk_exp<<<dim3(136, 1, BATCH), 256, 0, stream>>>(qb, kb, attn, psum);

    pv_mfma<<<512, 256, 0, stream>>>(attn, vT, psum, out);
}

// Round 24
// 146.269 us; speedup vs baseline: 1.0512x; 1.0512x over previous
//
#include <hip/hip_runtime.h>
#include <math.h>

#define BATCH 4
#define SEQ   2048
#define DM    1024
#define NTOK  (BATCH * SEQ)   // 8192

typedef __attribute__((ext_vector_type(8))) short bf16x8;
typedef __attribute__((ext_vector_type(4))) float f32x4;
typedef unsigned short u16;
struct alignas(8) us4 { u16 x, y, z, w; };

__device__ __forceinline__ u16 f2bf(float f) {
    union { float f; unsigned u; } v; v.f = f;
    unsigned r = v.u + 0x7fffu + ((v.u >> 16) & 1u);   // round-to-nearest-even
    return (u16)(r >> 16);
}

__device__ __forceinline__ void gload_lds16(const void* g, void* l) {
    __builtin_amdgcn_global_load_lds(
        (const __attribute__((address_space(1))) unsigned int*)g,
        (__attribute__((address_space(3))) unsigned int*)l, 16, 0, 0);
}

#define VM0 asm volatile("s_waitcnt vmcnt(0)" ::: "memory")
#define BAR __builtin_amdgcn_s_barrier()

// read one 16x16x32 fragment from a swizzled [128/256][64] tile
// (rows of 128 B, byte ^= (row&7)<<4 — conflict-free, verified R11/R13)
__device__ __forceinline__ bf16x8 ldsF(const u16* T, int fr, int kk, int lane)
{
    const int row  = fr * 16 + (lane & 15);
    const int colb = (kk * 64 + ((lane >> 4) << 4)) ^ ((row & 7) << 4);
    return *(const bf16x8*)(T + row * 64 + (colb >> 1));
}

// ===========================================================================
// qkv: 256x256 8-wave GEMM, one barrier per K-tile, R19 stage placement,
// R21 LDS-transpose vT epilogue (net win). Direct q/k stores (R23's LDS
// epilogue for q/k regressed and is reverted).
// ===========================================================================

// stage one 128-row x 64-k half (16 KB): 512 thr x 2 x 16 B
__device__ __forceinline__ void stageH(const u16* __restrict__ G, int ld,
    int row0, int kt, u16* half_lds, int wid, int lane)
{
    #pragma unroll
    for (int j = 0; j < 2; ++j) {
        const int base = j * 8192 + wid * 1024;           // dest byte
        const int off  = base + lane * 16;
        const int row  = off >> 7;                        // 0..127
        const int colb = (off & 127) ^ ((row & 7) << 4);  // inv-swz source col
        gload_lds16(G + (size_t)(row0 + row) * ld + kt + (colb >> 1),
                    (char*)half_lds + base);
    }
}

template<int MB, int NB>
__device__ __forceinline__ void mma16(const bf16x8 A[4][2], const bf16x8 B[2][2],
                                      f32x4 acc[8][4])
{
    __builtin_amdgcn_s_setprio(1);
    #pragma unroll
    for (int i = 0; i < 4; ++i)
        #pragma unroll
        for (int j = 0; j < 2; ++j)
            #pragma unroll
            for (int kk = 0; kk < 2; ++kk)
                acc[MB + i][NB + j] = __builtin_amdgcn_mfma_f32_16x16x32_bf16(
                    A[i][kk], B[j][kk], acc[MB + i][NB + j], 0, 0, 0);
    __builtin_amdgcn_s_setprio(0);
}

__global__ __launch_bounds__(512, 2) void qkv_mfma8(
    const u16* __restrict__ xb,
    const u16* __restrict__ wqb, const float* __restrict__ bq,
    const u16* __restrict__ wkb, const float* __restrict__ bk,
    const u16* __restrict__ wvb, const float* __restrict__ bv,
    u16* __restrict__ qb, u16* __restrict__ kb, u16* __restrict__ vT)
{
    __shared__ alignas(16) u16 LDS[65536];   // 128 KB
    const int z = blockIdx.z;
    const u16* W = (z == 0) ? wqb : (z == 1) ? wkb : wvb;
    const float* bias = (z == 0) ? bq : (z == 1) ? bk : bv;
    const int m0 = blockIdx.x * 256, n0 = blockIdx.y * 256;
    const int t = threadIdx.x, wid = t >> 6, lane = t & 63;
    const int wm = wid >> 2, wn = wid & 3;

    f32x4 acc[8][4] = {};

    // prologue: stage ALL 4 halves of tile 0 into parity-0 buffers
    stageH(xb, DM, m0,       0, LDS + 0,            wid, lane);  // A0 t0
    stageH(xb, DM, m0 + 128, 0, LDS + 8192,         wid, lane);  // A1 t0
    stageH(W,  DM, n0,       0, LDS + 32768,        wid, lane);  // B0 t0
    stageH(W,  DM, n0 + 128, 0, LDS + 32768 + 8192, wid, lane);  // B1 t0
    VM0;
    BAR;

    bf16x8 rA0[4][2], rA1[4][2], rB[2][2];

    #pragma unroll 1
    for (int ti = 0; ti < 16; ++ti) {
        const int cur = ti & 1, nxt = cur ^ 1;
        u16* Ac0 = LDS + cur * 16384;
        u16* Ac1 = Ac0 + 8192;
        u16* Bc0 = LDS + 32768 + cur * 16384;
        u16* Bc1 = Bc0 + 8192;
        u16* An0 = LDS + nxt * 16384;
        u16* An1 = An0 + 8192;
        u16* Bn0 = LDS + 32768 + nxt * 16384;
        u16* Bn1 = Bn0 + 8192;
        const int kt1 = (ti + 1) * 64;
        const bool st = ti < 15;

        // ---- straight-line region (R19 placement: stages interleaved) ----
        #pragma unroll
        for (int i = 0; i < 4; ++i) {
            rA0[i][0] = ldsF(Ac0, 2 * i + wm, 0, lane);
            rA0[i][1] = ldsF(Ac0, 2 * i + wm, 1, lane);
        }
        #pragma unroll
        for (int j = 0; j < 2; ++j) {
            rB[j][0] = ldsF(Bc0, 4 * j + wn, 0, lane);
            rB[j][1] = ldsF(Bc0, 4 * j + wn, 1, lane);
        }
        if (st) {
            stageH(xb, DM, m0,       kt1, An0, wid, lane);
            stageH(W,  DM, n0,       kt1, Bn0, wid, lane);
        }
        mma16<0, 0>(rA0, rB, acc);

        #pragma unroll
        for (int i = 0; i < 4; ++i) {
            rA1[i][0] = ldsF(Ac1, 2 * i + wm, 0, lane);
            rA1[i][1] = ldsF(Ac1, 2 * i + wm, 1, lane);
        }
        if (st) stageH(xb, DM, m0 + 128, kt1, An1, wid, lane);
        mma16<4, 0>(rA1, rB, acc);

        #pragma unroll
        for (int j = 0; j < 2; ++j) {
            rB[j][0] = ldsF(Bc1, 4 * j + wn, 0, lane);
            rB[j][1] = ldsF(Bc1, 4 * j + wn, 1, lane);
        }
        if (st) stageH(W, DM, n0 + 128, kt1, Bn1, wid, lane);
        mma16<4, 2>(rA1, rB, acc);

        mma16<0, 2>(rA0, rB, acc);

        // ---- single sync point per K-tile ----
        VM0;
        BAR;
    }

    const int lrow = lane & 15, lhi = lane >> 4;
    if (z < 2) {
        u16* outp = (z == 0) ? qb : kb;
        #pragma unroll
        for (int nf = 0; nf < 4; ++nf) {
            const int n = n0 + (4 * nf + wn) * 16 + lrow;
            const float bn = bias[n];
            #pragma unroll
            for (int mf = 0; mf < 8; ++mf) {
                const int mb = m0 + (2 * mf + wm) * 16 + lhi * 4;
                #pragma unroll
                for (int r = 0; r < 4; ++r)
                    outp[(size_t)(mb + r) * DM + n] = f2bf(acc[mf][nf][r] + bn);
            }
        }
    } else {
        // ---- vT via LDS transpose: LDS free after final BAR ----
        #pragma unroll
        for (int nf = 0; nf < 4; ++nf) {
            const int nloc = nf * 16 + lrow;
            const int n = n0 + (4 * nf + wn) * 16 + lrow;
            const float bn = bias[n];
            #pragma unroll
            for (int mf = 0; mf < 8; ++mf) {
                const int mloc0 = (2 * mf + wm) * 16 + lhi * 4;
                const int idx = (wn * 16384 + nloc * 256 + mloc0)
                                ^ ((nloc & 7) << 3);
                us4 p{f2bf(acc[mf][nf][0] + bn), f2bf(acc[mf][nf][1] + bn),
                      f2bf(acc[mf][nf][2] + bn), f2bf(acc[mf][nf][3] + bn)};
                *(us4*)(LDS + idx) = p;
            }
        }
        BAR;
        const int c = t & 31;            // 16B chunk within the 512B row
        #pragma unroll 1
        for (int rr = t >> 5; rr < 256; rr += 16) {
            const int lr2 = rr & 15, wn2 = (rr >> 4) & 3, nf2 = rr >> 6;
            const int nloc = nf2 * 16 + lr2;
            const int idx = (wn2 * 16384 + nloc * 256 + c * 8)
                            ^ ((nloc & 7) << 3);
            bf16x8 v = *(const bf16x8*)(LDS + idx);
            *(bf16x8*)(vT + (size_t)(n0 + rr) * NTOK + m0 + c * 8) = v;
        }
    }
}

// ===========================================================================
// qk / pv: BK=64 + swizzle, 2-barrier 128x128 structure.
// ===========================================================================

// Stage a 128-row x 64-k bf16 tile (16 KB) into swizzled LDS, 256 thr.
__device__ __forceinline__ void stage64(const u16* __restrict__ G, int ld,
    int row0, int kt, u16* lds, int wid, int lane)
{
    #pragma unroll
    for (int j = 0; j < 4; ++j) {
        const int base = j * 4096 + wid * 1024;
        const int off  = base + lane * 16;
        const int row  = off >> 7;
        const int colb = (off & 127) ^ ((row & 7) << 4);
        gload_lds16(G + (size_t)(row0 + row) * ld + kt + (colb >> 1),
                    (char*)lds + base);
    }
}

// 16 ds_reads -> 32 MFMAs per K=64 tile (4 waves, 64x64 each)
__device__ __forceinline__ void frag_mma64(
    const u16* As, const u16* Bs, int wr, int wc, int lane, f32x4 acc[4][4])
{
    #pragma unroll
    for (int kk = 0; kk < 2; ++kk) {
        bf16x8 a[4], b[4];
        #pragma unroll
        for (int i = 0; i < 4; ++i) a[i] = ldsF(As, wr * 4 + i, kk, lane);
        #pragma unroll
        for (int j = 0; j < 4; ++j) b[j] = ldsF(Bs, wc * 4 + j, kk, lane);
        #pragma unroll
        for (int i = 0; i < 4; ++i)
            #pragma unroll
            for (int j = 0; j < 4; ++j)
                acc[i][j] = __builtin_amdgcn_mfma_f32_16x16x32_bf16(
                    a[i], b[j], acc[i][j], 0, 0, 0);
    }
}

// ---------------------------------------------------------------------------
// f32 -> bf16 convert: flat balanced grid over all four arrays (66 MB total).
// ---------------------------------------------------------------------------
__global__ __launch_bounds__(256) void conv_flat(
    const float* __restrict__ x,
    const float* __restrict__ w0, const float* __restrict__ w1,
    const float* __restrict__ w2,
    u16* __restrict__ xo,
    u16* __restrict__ o0, u16* __restrict__ o1, u16* __restrict__ o2)
{
    const int X4  = NTOK * DM / 4;     // 2,097,152 float4s
    const int W4  = DM * DM / 4;       //   262,144 float4s
    const int TOT = X4 + 3 * W4;
    for (int i = blockIdx.x * 256 + threadIdx.x; i < TOT; i += gridDim.x * 256) {
        const float* in; u16* out; int idx;
        if (i < X4) { in = x; out = xo; idx = i; }
        else {
            const int j = i - X4, s = j >> 18;       // /W4 (2^18)
            idx = j & (W4 - 1);
            in  = (s == 0) ? w0 : (s == 1) ? w1 : w2;
            out = (s == 0) ? o0 : (s == 1) ? o1 : o2;
        }
        float4 f = ((const float4*)in)[idx];
        us4 p{f2bf(f.x), f2bf(f.y), f2bf(f.z), f2bf(f.w)};
        ((us4*)out)[idx] = p;
    }
}

__global__ __launch_bounds__(256, 3) void qk_exp(
    const u16* __restrict__ qb, const u16* __restrict__ kb,
    u16* __restrict__ attn, float* __restrict__ psum)
{
    const int m0 = blockIdx.x * 128, n0 = blockIdx.y * 128;
    if (n0 > m0) return;
    __shared__ u16 As[128 * 64], Bs[128 * 64];   // 32 KB
    const int b = blockIdx.z;
    const u16* A = qb + (size_t)b * SEQ * DM;
    const u16* B = kb + (size_t)b * SEQ * DM;
    u16* P = attn + (size_t)b * SEQ * SEQ;
    const int t = threadIdx.x, wid = t >> 6, lane = t & 63;
    const int wr = wid >> 1, wc = wid & 1;

    f32x4 acc[4][4] = {};
    for (int kt = 0; kt < DM; kt += 64) {
        __syncthreads();
        stage64(A, DM, m0, kt, As, wid, lane);
        stage64(B, DM, n0, kt, Bs, wid, lane);
        __syncthreads();
        frag_mma64(As, Bs, wr, wc, lane, acc);
    }
    const int lrow = lane & 15, lg = lane >> 4;
    const float scale = 0.03125f;
    const int nb = (n0 >> 6) | wc;
    #pragma unroll
    for (int mi = 0; mi < 4; ++mi) {
        #pragma unroll
        for (int r = 0; r < 4; ++r) {
            const int row = m0 + wr * 64 + mi * 16 + lg * 4 + r;
            float ps = 0.f;
            #pragma unroll
            for (int ni = 0; ni < 4; ++ni) {
                const int n = n0 + wc * 64 + ni * 16 + lrow;
                const float p = (n <= row) ? __expf(acc[mi][ni][r] * scale) : 0.f;
                P[(size_t)row * SEQ + n] = f2bf(p);
                ps += p;
            }
            #pragma unroll
            for (int mk = 1; mk < 16; mk <<= 1) ps += __shfl_xor(ps, mk);
            if (lrow == 0)
                psum[((size_t)b * SEQ + row) * 32 + nb] = ps;
        }
    }
}

// pv: 1-D grid (512) with XCD-clustering swizzle (bijective, perf-only).
__global__ __launch_bounds__(256, 3) void pv_mfma(
    const u16* __restrict__ attn, const u16* __restrict__ vT,
    const float* __restrict__ psum, float* __restrict__ out)
{
    __shared__ u16 As[128 * 64], Bs[128 * 64];   // 32 KB
    __shared__ float invs[128];
    const int bid = blockIdx.x;
    const int xcd = bid & 7, rdec = bid >> 3;
    const int n0i = rdec & 7, ghi = rdec >> 3;
    const int g = ghi * 8 + xcd;          // g = m0i + 16*b
    const int m0 = (g & 15) * 128, n0 = n0i * 128;
    const int b = g >> 4;
    const u16* A = attn + (size_t)b * SEQ * SEQ;
    const u16* B = vT + (size_t)b * SEQ;
    float* C = out + (size_t)b * SEQ * DM;
    const int t = threadIdx.x, wid = t >> 6, lane = t & 63;
    const int wr = wid >> 1, wc = wid & 1;

    if (t < 128) {
        const int row = m0 + t;
        const float* pr = psum + ((size_t)b * SEQ + row) * 32;
        const int nbmax = (row >> 6) | 1;
        float s = 0.f;
        for (int nbi = 0; nbi <= nbmax; ++nbi) s += pr[nbi];
        invs[t] = 1.f / s;
    }

    f32x4 acc[4][4] = {};
    const int kmax = m0 + 128;
    for (int kt = 0; kt < kmax; kt += 64) {
        __syncthreads();
        stage64(A, SEQ,  m0, kt, As, wid, lane);
        stage64(B, NTOK, n0, kt, Bs, wid, lane);
        __syncthreads();
        frag_mma64(As, Bs, wr, wc, lane, acc);
    }
    const int lrow = lane & 15, lg = lane >> 4;
    #pragma unroll
    for (int mi = 0; mi < 4; ++mi) {
        const int ml = wr * 64 + mi * 16 + lg * 4;
        #pragma unroll
        for (int ni = 0; ni < 4; ++ni) {
            const int n = n0 + wc * 64 + ni * 16 + lrow;
            #pragma unroll
            for (int r = 0; r < 4; ++r)
                C[(size_t)(m0 + ml + r) * DM + n] = acc[mi][ni][r] * invs[ml + r];
        }
    }
}

// ---------------------------------------------------------------------------
extern "C" void kernel_launch(void* const* d_in, const int* in_sizes, int n_in,
                              void* d_out, int out_size, void* d_ws, size_t ws_size,
                              hipStream_t stream)
{
    const float* x  = (const float*)d_in[0];
    const float* wq = (const float*)d_in[1];
    const float* bq = (const float*)d_in[2];
    const float* wk = (const float*)d_in[3];
    const float* bk = (const float*)d_in[4];
    const float* wv = (const float*)d_in[5];
    const float* bv = (const float*)d_in[6];
    float* out = (float*)d_out;

    u16* ws  = (u16*)d_ws;
    u16* xb  = ws;
    u16* wqb = xb  + (size_t)NTOK * DM;
    u16* wkb = wqb + (size_t)DM * DM;
    u16* wvb = wkb + (size_t)DM * DM;
    u16* qb  = wvb + (size_t)DM * DM;
    u16* kb  = qb  + (size_t)NTOK * DM;
    u16* vT  = kb  + (size_t)NTOK * DM;        // [DM][NTOK]
    u16* attn = vT + (size_t)NTOK * DM;        // bf16 [B][SEQ][SEQ]
    float* psum = (float*)(attn + (size_t)BATCH * SEQ * SEQ);  // [B][SEQ][32]

    conv_flat<<<2048, 256, 0, stream>>>(
        x, wq, wk, wv, xb, wqb, wkb, wvb);

    qkv_mfma8<<<dim3(NTOK / 256, DM / 256, 3), 512, 0, stream>>>(
        xb, wqb, bq, wkb, bk, wvb, bv, qb, kb, vT);

    qk_exp<<<dim3(SEQ / 128, SEQ / 128, BATCH), 256, 0, stream>>>(
        qb, kb, attn, psum);

    pv_mfma<<<512, 256, 0, stream>>>(attn, vT, psum, out);
}